// Round 1
// 35520.285 us; speedup vs baseline: 26.5526x; 26.5526x over previous
//
#include <hip/hip_runtime.h>

// MultilayerGRU: B=64 S=512 I=128 H=1024 L=3 O=128, fp32.
//
// R10: full restructure from "1 WG per batch, sequential dots" (943 ms,
// VALUBusy 2.2%) to batched split-K GEMMs with a layer-wavefront pipeline.
//
//  - All activations kept TRANSPOSED [k][b] so the GEMM K-loop reads
//    contiguous [K][64] panels; weights pre-transposed to W^T[k][n].
//  - Tick tau: layer l computes t=tau-l; y_t computed at tau=t+3.
//    Per tick: GEMM-A (r preacts + g's x-part + y) -> reduceA (sigma, r*h) ->
//    GEMM-B (z preacts + g's h-part) -> reduceB (z, tanh, h-update).
//    Kernel boundaries provide the r-dependency sync.
//  - Split-K: tasks of <=640 k so phase A = 244 WGs, phase B = 256 WGs
//    (~1 per CU). Each WG: 64x64 tile, 4x4 micro-tile/thread, LDS-staged.
//  - h double-buffered by tick parity; both buffers zeroed per call.

namespace {
constexpr int kB = 64, kS = 512, kI = 128, kH = 1024, kO = 128;
constexpr int kTicks = kS + 3;               // tau = 0..514
constexpr size_t kBSO = (size_t)kB * kS * kO;

// Workspace (device globals; ~94 MB total)
__device__ float g_wxt0[3 * 128 * 1024];     // Wx0^T  [gate][k=I][n=H]
__device__ float g_wht0[3 * 1024 * 1024];    // Wh0^T  [gate][k][n]
__device__ float g_wxtr[6 * 1024 * 1024];    // Wxr^T  [(l-1)*3+gate][k][n]
__device__ float g_whtr[6 * 1024 * 1024];    // Whr^T
__device__ float g_woutT[1024 * 128];        // Wout^T [k=H][o=O]
__device__ float g_xT[512 * 128 * 64];       // x^T    [t][i][b]
__device__ float g_hbuf[2 * 3 * 1024 * 64];  // h^T    [parity][l][n][b]
__device__ float g_rhT[3 * 1024 * 64];       // (r*h)^T[l][n][b]
__device__ float g_gxT[3 * 1024 * 64];       // g x-part + bias
__device__ float g_partA[244 * 4096];        // split-K partials [task][cl][b]
__device__ float g_partB[256 * 4096];
}  // namespace

// ---------------- setup kernels ----------------

__global__ void zero_hbuf() {
  g_hbuf[blockIdx.x * 256 + threadIdx.x] = 0.f;
}

// out[c][r] = in[r][c], batched over blockIdx.z. sel picks destination.
__global__ __launch_bounds__(256) void transpose_k(
    const float* __restrict__ in, int sel, int R, int C) {
  float* out;
  switch (sel) {
    case 0: out = g_wxt0; break;
    case 1: out = g_wht0; break;
    case 2: out = g_wxtr; break;
    case 3: out = g_whtr; break;
    case 4: out = g_woutT; break;
    default: out = g_xT; break;
  }
  const size_t mat = (size_t)R * C;
  in += blockIdx.z * mat;
  out += blockIdx.z * mat;
  __shared__ float t[32][33];
  const int c0 = blockIdx.x * 32, r0 = blockIdx.y * 32;
  const int tx = threadIdx.x & 31, ty = threadIdx.x >> 5;
  for (int i = ty; i < 32; i += 8) {
    const int r = r0 + i, c = c0 + tx;
    if (r < R && c < C) t[i][tx] = in[(size_t)r * C + c];
  }
  __syncthreads();
  for (int i = ty; i < 32; i += 8) {
    const int c = c0 + i, r = r0 + tx;
    if (c < C && r < R) out[(size_t)c * R + r] = t[tx][i];
  }
}

// ---------------- main GEMM (split-K tasks) ----------------
// out tile: 64 cols (n) x 64 batch. part[task][cl][b] = sum_k WT[k][n0+cl]*inpT[k][b]
//
// phase 0 (A): role0 = r-gate preacts, role1 = g x-part, role2 = y
// phase 1 (B): role0 = z-gate preacts, role3 = g h-part (inp = (r*h)^T)
__global__ __launch_bounds__(256) void gemm_tasks(int phase, int tau) {
  const int id = blockIdx.x;
  const int par = tau & 1;
  const float* hb = g_hbuf + par * 196608;  // [l][n][b]

  int l = 0, tile = 0, ks = 0, role;
  if (id < 32) { l = 0; tile = id >> 1; ks = id & 1; role = 0; }
  else if (id < 96)  { int q = id - 32;  l = 1; tile = q >> 2; ks = q & 3; role = 0; }
  else if (id < 160) { int q = id - 96;  l = 2; tile = q >> 2; ks = q & 3; role = 0; }
  else if (phase == 0) {
    if (id < 176)      { l = 0; tile = id - 160; ks = 0; role = 1; }
    else if (id < 208) { int q = id - 176; l = 1; tile = q >> 1; ks = q & 1; role = 1; }
    else if (id < 240) { int q = id - 208; l = 2; tile = q >> 1; ks = q & 1; role = 1; }
    else               { int q = id - 240; tile = q >> 1; ks = q & 1; role = 2; }
  } else {
    int q = id - 160; l = q >> 5; q &= 31; tile = q >> 1; ks = q & 1; role = 3;
  }

  const int n0 = tile * 64;
  const float* inp = nullptr; const float* w = nullptr;
  const float* inp2 = nullptr; const float* w2 = nullptr;
  int nk = 0, nk2 = 0, ldw = 1024, t_l;

  if (role == 0) {
    const int gate = (phase == 0) ? 1 : 0;  // r or z
    t_l = tau - l;
    if (l == 0) {
      const float* wh = g_wht0 + (size_t)gate * 1048576;
      if (ks == 0) {  // x-part (K=128) + first half of h-part
        inp = g_xT + (size_t)t_l * 8192; nk = 128;
        w = g_wxt0 + (size_t)gate * 131072 + n0;
        inp2 = hb; nk2 = 512; w2 = wh + n0;
      } else {        // second half of h-part
        inp = hb + 32768; nk = 512; w = wh + 524288 + n0;
      }
    } else {
      const float* wx = g_wxtr + (size_t)((l - 1) * 3 + gate) * 1048576;
      const float* wh = g_whtr + (size_t)((l - 1) * 3 + gate) * 1048576;
      if (ks < 2) { inp = hb + (l - 1) * 65536 + ks * 32768; nk = 512;
                    w = wx + (size_t)ks * 524288 + n0; }
      else        { inp = hb + l * 65536 + (ks - 2) * 32768; nk = 512;
                    w = wh + (size_t)(ks - 2) * 524288 + n0; }
    }
  } else if (role == 1) {  // g x-part
    t_l = tau - l;
    if (l == 0) { inp = g_xT + (size_t)t_l * 8192; nk = 128;
                  w = g_wxt0 + (size_t)2 * 131072 + n0; }
    else { inp = hb + (l - 1) * 65536 + ks * 32768; nk = 512;
           w = g_wxtr + (size_t)((l - 1) * 3 + 2) * 1048576 + (size_t)ks * 524288 + n0; }
  } else if (role == 2) {  // y = h2 @ Wout^T
    t_l = tau - 3;
    inp = hb + 2 * 65536 + ks * 32768; nk = 512;
    w = g_woutT + (size_t)ks * 65536 + n0; ldw = 128;
  } else {                 // g h-part: (r*h) @ Whg^T
    t_l = tau - l;
    inp = g_rhT + l * 65536 + ks * 32768; nk = 512;
    w = ((l == 0) ? g_wht0 + (size_t)2 * 1048576
                  : g_whtr + (size_t)((l - 1) * 3 + 2) * 1048576) +
        (size_t)ks * 524288 + n0;
  }
  if (t_l < 0 || t_l >= kS) return;  // layer inactive this tick

  __shared__ float sI[64 * 64];  // [k][b]
  __shared__ float sW[64 * 64];  // [k][n]
  const int tid = threadIdx.x;
  const int tn = (tid & 15) * 4, tb = (tid >> 4) * 4;
  float acc[4][4] = {};

  for (int seg = 0; seg < 2; ++seg) {
    const float* ip; const float* wp; int kn;
    if (seg == 0) { ip = inp; wp = w; kn = nk; }
    else { if (!nk2) break; ip = inp2; wp = w2; kn = nk2; }
    for (int c0 = 0; c0 < kn; c0 += 64) {
      const float4* s4 = (const float4*)(ip + c0 * 64);
      float4* d4 = (float4*)sI;
#pragma unroll
      for (int u = 0; u < 4; ++u) d4[tid + u * 256] = s4[tid + u * 256];
#pragma unroll
      for (int u = 0; u < 4; ++u) {
        const int idx = tid + u * 256, k = idx >> 4, f = idx & 15;
        ((float4*)sW)[idx] = *(const float4*)(wp + (size_t)(c0 + k) * ldw + f * 4);
      }
      __syncthreads();
#pragma unroll 8
      for (int k = 0; k < 64; ++k) {
        const float4 a = *(const float4*)(sI + k * 64 + tb);
        const float4 wv = *(const float4*)(sW + k * 64 + tn);
        acc[0][0] += wv.x * a.x; acc[0][1] += wv.x * a.y; acc[0][2] += wv.x * a.z; acc[0][3] += wv.x * a.w;
        acc[1][0] += wv.y * a.x; acc[1][1] += wv.y * a.y; acc[1][2] += wv.y * a.z; acc[1][3] += wv.y * a.w;
        acc[2][0] += wv.z * a.x; acc[2][1] += wv.z * a.y; acc[2][2] += wv.z * a.z; acc[2][3] += wv.z * a.w;
        acc[3][0] += wv.w * a.x; acc[3][1] += wv.w * a.y; acc[3][2] += wv.w * a.z; acc[3][3] += wv.w * a.w;
      }
      __syncthreads();
    }
  }

  float* po = ((phase == 0) ? g_partA : g_partB) + (size_t)id * 4096;
#pragma unroll
  for (int i = 0; i < 4; ++i) {
    float4 v = {acc[i][0], acc[i][1], acc[i][2], acc[i][3]};
    *(float4*)(po + (tn + i) * 64 + tb) = v;
  }
}

// ---------------- reduce A: r = sigma(.), rh^T, gx^T, y ----------------
__global__ __launch_bounds__(256) void reduceA(
    int tau, const float* __restrict__ Bh0, const float* __restrict__ Bhr,
    const float* __restrict__ Bout, float* __restrict__ Out) {
  const int gid = blockIdx.x * 256 + threadIdx.x;  // < 6272*64
  const int b = gid & 63, c = gid >> 6;
  const int par = tau & 1;
  if (c < 3072) {  // r-gate
    const int l = c >> 10, n = c & 1023;
    const int t_l = tau - l;
    if (t_l < 0 || t_l >= kS) return;
    const int tile = n >> 6, cl = n & 63;
    int base, nks;
    if (l == 0)      { base = tile * 2;      nks = 2; }
    else if (l == 1) { base = 32 + tile * 4; nks = 4; }
    else             { base = 96 + tile * 4; nks = 4; }
    float s = (l == 0) ? Bh0[1024 + n] : Bhr[(l - 1) * 3072 + 1024 + n];
    for (int j = 0; j < nks; ++j) s += g_partA[(size_t)(base + j) * 4096 + cl * 64 + b];
    const float r = 1.f / (1.f + expf(-s));
    const float h = g_hbuf[par * 196608 + l * 65536 + n * 64 + b];
    g_rhT[l * 65536 + n * 64 + b] = r * h;
  } else if (c < 6144) {  // g x-part + bias
    const int cc = c - 3072, l = cc >> 10, n = cc & 1023;
    const int t_l = tau - l;
    if (t_l < 0 || t_l >= kS) return;
    const int tile = n >> 6, cl = n & 63;
    int base, nks;
    if (l == 0)      { base = 160 + tile;     nks = 1; }
    else if (l == 1) { base = 176 + tile * 2; nks = 2; }
    else             { base = 208 + tile * 2; nks = 2; }
    float s = (l == 0) ? Bh0[2048 + n] : Bhr[(l - 1) * 3072 + 2048 + n];
    for (int j = 0; j < nks; ++j) s += g_partA[(size_t)(base + j) * 4096 + cl * 64 + b];
    g_gxT[l * 65536 + n * 64 + b] = s;
  } else {  // y
    const int o = c - 6144, ty = tau - 3;
    if (ty < 0 || ty >= kS) return;
    const int tile = o >> 6, cl = o & 63, base = 240 + tile * 2;
    float s = Bout[o];
    s += g_partA[(size_t)base * 4096 + cl * 64 + b];
    s += g_partA[(size_t)(base + 1) * 4096 + cl * 64 + b];
    Out[((size_t)b * kS + ty) * kO + o] = s;
  }
}

// ---------------- reduce B: z, g=tanh, h' = z*h + (1-z)*g ----------------
__global__ __launch_bounds__(256) void reduceB(
    int tau, const float* __restrict__ Bh0, const float* __restrict__ Bhr,
    float* __restrict__ Out) {
  const int gid = blockIdx.x * 256 + threadIdx.x;  // < 3072*64
  const int b = gid & 63, c = gid >> 6;
  const int l = c >> 10, n = c & 1023;
  const int t_l = tau - l;
  if (t_l < 0 || t_l >= kS) return;
  const int par = tau & 1;
  const int tile = n >> 6, cl = n & 63;
  int zbase, znks;
  if (l == 0)      { zbase = tile * 2;      znks = 2; }
  else if (l == 1) { zbase = 32 + tile * 4; znks = 4; }
  else             { zbase = 96 + tile * 4; znks = 4; }
  float zs = (l == 0) ? Bh0[n] : Bhr[(l - 1) * 3072 + n];
  for (int j = 0; j < znks; ++j) zs += g_partB[(size_t)(zbase + j) * 4096 + cl * 64 + b];
  const float z = 1.f / (1.f + expf(-zs));
  const int gbase = 160 + l * 32 + tile * 2;
  float gs = g_gxT[l * 65536 + n * 64 + b];
  gs += g_partB[(size_t)gbase * 4096 + cl * 64 + b];
  gs += g_partB[(size_t)(gbase + 1) * 4096 + cl * 64 + b];
  const float g = tanhf(gs);
  const float h = g_hbuf[par * 196608 + l * 65536 + n * 64 + b];
  const float hn = z * h + (1.f - z) * g;
  g_hbuf[(1 - par) * 196608 + l * 65536 + n * 64 + b] = hn;
  if (t_l == kS - 1)
    Out[kBSO + ((size_t)b * 3 + l) * 1024 + n] = hn;
}

// ---------------- host ----------------
extern "C" void kernel_launch(void* const* d_in, const int* in_sizes, int n_in,
                              void* d_out, int out_size, void* d_ws, size_t ws_size,
                              hipStream_t stream) {
  const float* X    = (const float*)d_in[0];
  const float* Wx0  = (const float*)d_in[1];
  const float* Wh0  = (const float*)d_in[2];
  const float* bh0  = (const float*)d_in[3];
  const float* Wxr  = (const float*)d_in[4];
  const float* Whr  = (const float*)d_in[5];
  const float* bhr  = (const float*)d_in[6];
  const float* Wout = (const float*)d_in[7];
  const float* bout = (const float*)d_in[8];
  (void)d_ws; (void)ws_size;

  if (n_in != 9 ||
      in_sizes[0] != 64 * 512 * 128 || in_sizes[1] != 3 * 1024 * 128 ||
      in_sizes[2] != 3 * 1024 * 1024 || in_sizes[3] != 3 * 1024 ||
      in_sizes[4] != 2 * 3 * 1024 * 1024 || in_sizes[5] != 2 * 3 * 1024 * 1024 ||
      in_sizes[6] != 2 * 3 * 1024 || in_sizes[7] != 128 * 1024 ||
      in_sizes[8] != 128 || out_size != 64 * 512 * 128 + 64 * 3 * 1024)
    return;  // diagnostic: out stays 0

  float* out = (float*)d_out;

  hipLaunchKernelGGL(zero_hbuf, dim3(1536), dim3(256), 0, stream);
  hipLaunchKernelGGL(transpose_k, dim3(4, 32, 3),   dim3(256), 0, stream, Wx0,  0, 1024, 128);
  hipLaunchKernelGGL(transpose_k, dim3(32, 32, 3),  dim3(256), 0, stream, Wh0,  1, 1024, 1024);
  hipLaunchKernelGGL(transpose_k, dim3(32, 32, 6),  dim3(256), 0, stream, Wxr,  2, 1024, 1024);
  hipLaunchKernelGGL(transpose_k, dim3(32, 32, 6),  dim3(256), 0, stream, Whr,  3, 1024, 1024);
  hipLaunchKernelGGL(transpose_k, dim3(32, 4, 1),   dim3(256), 0, stream, Wout, 4, 128, 1024);
  hipLaunchKernelGGL(transpose_k, dim3(2048, 2, 1), dim3(256), 0, stream, X,    5, 64, 65536);

  for (int tau = 0; tau < kTicks; ++tau) {
    hipLaunchKernelGGL(gemm_tasks, dim3(244), dim3(256), 0, stream, 0, tau);
    hipLaunchKernelGGL(reduceA, dim3(1568), dim3(256), 0, stream,
                       tau, bh0, bhr, bout, out);
    if (tau < kTicks - 1) {
      hipLaunchKernelGGL(gemm_tasks, dim3(256), dim3(256), 0, stream, 1, tau);
      hipLaunchKernelGGL(reduceB, dim3(768), dim3(256), 0, stream,
                         tau, bh0, bhr, out);
    }
  }
}

// Round 2
// 26450.839 us; speedup vs baseline: 35.6569x; 1.3429x over previous
//
#include <hip/hip_runtime.h>

// MultilayerGRU: B=64 S=512 I=128 H=1024 L=3 O=128, fp32.
//
// R11: occupancy + phase-rebalance pass on R10's split-K wavefront design.
//  - z-gate GEMM moved from phase B to phase A (z only feeds the h-update,
//    not the r-dependency). A = {z, r preacts, g x-part, y} = 1.68 GFLOP;
//    B = {g h-part} = 0.40 GFLOP.
//  - Finer split-K: tasks of <=384 k. Phase A = 792 WGs, phase B = 384 WGs
//    (~2-3 WGs/CU vs R10's ~1/CU = 1 wave/SIMD). With __launch_bounds__(256,2)
//    and 32 KiB LDS, two blocks co-reside per CU -> 2 waves/SIMD hide LDS
//    latency; GEMMs should approach the ~89% FMA-issue-density floor.
//  - reduceA applies sigma to BOTH z and r (z cached in g_zT), computes r*h
//    and gx; reduceB does tanh + h-update only.

namespace {
constexpr int kB = 64, kS = 512, kI = 128, kH = 1024, kO = 128;
constexpr int kTicks = kS + 3;               // tau = 0..514
constexpr size_t kBSO = (size_t)kB * kS * kO;
constexpr int kTasksA = 792, kTasksB = 384;

// Workspace (device globals; ~100 MB total)
__device__ float g_wxt0[3 * 128 * 1024];     // Wx0^T  [gate][k=I][n=H]
__device__ float g_wht0[3 * 1024 * 1024];    // Wh0^T  [gate][k][n]
__device__ float g_wxtr[6 * 1024 * 1024];    // Wxr^T  [(l-1)*3+gate][k][n]
__device__ float g_whtr[6 * 1024 * 1024];    // Whr^T
__device__ float g_woutT[1024 * 128];        // Wout^T [k=H][o=O]
__device__ float g_xT[512 * 128 * 64];       // x^T    [t][i][b]
__device__ float g_hbuf[2 * 3 * 1024 * 64];  // h^T    [parity][l][n][b]
__device__ float g_zT[3 * 1024 * 64];        // sigma(z) [l][n][b]
__device__ float g_rhT[3 * 1024 * 64];       // (r*h)^T[l][n][b]
__device__ float g_gxT[3 * 1024 * 64];       // g x-part + bias
__device__ float g_partA[kTasksA * 4096];    // split-K partials [task][cl][b]
__device__ float g_partB[kTasksB * 4096];
}  // namespace

// ---------------- setup kernels ----------------

__global__ void zero_hbuf() {
  g_hbuf[blockIdx.x * 256 + threadIdx.x] = 0.f;
}

// out[c][r] = in[r][c], batched over blockIdx.z. sel picks destination.
__global__ __launch_bounds__(256) void transpose_k(
    const float* __restrict__ in, int sel, int R, int C) {
  float* out;
  switch (sel) {
    case 0: out = g_wxt0; break;
    case 1: out = g_wht0; break;
    case 2: out = g_wxtr; break;
    case 3: out = g_whtr; break;
    case 4: out = g_woutT; break;
    default: out = g_xT; break;
  }
  const size_t mat = (size_t)R * C;
  in += blockIdx.z * mat;
  out += blockIdx.z * mat;
  __shared__ float t[32][33];
  const int c0 = blockIdx.x * 32, r0 = blockIdx.y * 32;
  const int tx = threadIdx.x & 31, ty = threadIdx.x >> 5;
  for (int i = ty; i < 32; i += 8) {
    const int r = r0 + i, c = c0 + tx;
    if (r < R && c < C) t[i][tx] = in[(size_t)r * C + c];
  }
  __syncthreads();
  for (int i = ty; i < 32; i += 8) {
    const int c = c0 + i, r = r0 + tx;
    if (c < C && r < R) out[(size_t)c * R + r] = t[tx][i];
  }
}

// ---------------- main GEMM (split-K tasks) ----------------
// out tile: 64 cols (n) x 64 batch. part[task][cl][b] = sum_k WT[k][n0+cl]*inpT[k][b]
//
// Phase A task map (792):
//   [  0,128) l0 z,r : id = gate*64 + tile*4 + ks   (ks0: x128+h[0:256); ks1-3: h 256-chunks)
//   [128,384) l1 z,r : 128 + gate*128 + tile*8 + ks (ks<4: x-part=h_{l-1}; ks>=4: h-part; 256k)
//   [384,640) l2 z,r : 384 + ...
//   [640,656) gx l0  : 640 + tile                   (K=128)
//   [656,720) gx l1  : 656 + tile*4 + ks            (256k)
//   [720,784) gx l2  : 720 + tile*4 + ks
//   [784,792) y      : 784 + tile*4 + ks            (256k)
// Phase B task map (384): gh: id = l*128 + tile*8 + ks (128k chunks)
__global__ __launch_bounds__(256, 2) void gemm_tasks(int phase, int tau) {
  const int id = blockIdx.x;
  const int par = tau & 1;
  const float* hb = g_hbuf + par * 196608;  // [l][n][b]

  int l = 0, t_l = 0;
  const float* inp = nullptr; const float* w = nullptr;
  const float* inp2 = nullptr; const float* w2 = nullptr;
  int nk = 0, nk2 = 0, ldw = 1024;

  if (phase == 0) {
    if (id < 128) {  // l0 z,r
      const int gate = id >> 6, rem = id & 63;
      const int tile = rem >> 2, ks = rem & 3, n0 = tile * 64;
      t_l = tau;
      const float* wh = g_wht0 + (size_t)gate * 1048576;
      if (ks == 0) {
        inp = g_xT + (size_t)t_l * 8192; nk = 128;
        w = g_wxt0 + (size_t)gate * 131072 + n0;
        inp2 = hb; nk2 = 256; w2 = wh + n0;
      } else {
        const int k0 = ks * 256;
        inp = hb + k0 * 64; nk = 256;
        w = wh + (size_t)k0 * 1024 + n0;
      }
    } else if (id < 640) {  // l1/l2 z,r
      const int q = id - 128;
      l = 1 + (q >> 8);
      const int qq = q & 255, gate = qq >> 7, rem = qq & 127;
      const int tile = rem >> 3, ks = rem & 7, n0 = tile * 64;
      t_l = tau - l;
      if (ks < 4) {
        const int k0 = ks * 256;
        inp = hb + (l - 1) * 65536 + k0 * 64; nk = 256;
        w = g_wxtr + (size_t)((l - 1) * 3 + gate) * 1048576 + (size_t)k0 * 1024 + n0;
      } else {
        const int k0 = (ks - 4) * 256;
        inp = hb + l * 65536 + k0 * 64; nk = 256;
        w = g_whtr + (size_t)((l - 1) * 3 + gate) * 1048576 + (size_t)k0 * 1024 + n0;
      }
    } else if (id < 656) {  // gx l0 (K=128)
      const int tile = id - 640;
      t_l = tau;
      inp = g_xT + (size_t)t_l * 8192; nk = 128;
      w = g_wxt0 + (size_t)2 * 131072 + tile * 64;
    } else if (id < 784) {  // gx l1/l2
      const int q = id - 656;
      l = 1 + (q >> 6);
      const int qq = q & 63, tile = qq >> 2, ks = qq & 3;
      t_l = tau - l;
      const int k0 = ks * 256;
      inp = hb + (l - 1) * 65536 + k0 * 64; nk = 256;
      w = g_wxtr + (size_t)((l - 1) * 3 + 2) * 1048576 + (size_t)k0 * 1024 + tile * 64;
    } else {  // y
      const int q = id - 784, tile = q >> 2, ks = q & 3;
      t_l = tau - 3;
      const int k0 = ks * 256;
      inp = hb + 2 * 65536 + k0 * 64; nk = 256;
      w = g_woutT + (size_t)k0 * 128 + tile * 64; ldw = 128;
    }
  } else {  // phase B: g h-part, inp = (r*h)^T
    l = id >> 7;
    const int rem = id & 127, tile = rem >> 3, ks = rem & 7;
    t_l = tau - l;
    const int k0 = ks * 128;
    inp = g_rhT + l * 65536 + k0 * 64; nk = 128;
    w = ((l == 0) ? g_wht0 + (size_t)2 * 1048576
                  : g_whtr + (size_t)((l - 1) * 3 + 2) * 1048576) +
        (size_t)k0 * 1024 + tile * 64;
  }
  if (t_l < 0 || t_l >= kS) return;  // inactive this tick

  __shared__ float sI[64 * 64];  // [k][b]
  __shared__ float sW[64 * 64];  // [k][n]
  const int tid = threadIdx.x;
  const int tn = (tid & 15) * 4, tb = (tid >> 4) * 4;
  float acc[4][4] = {};

  for (int seg = 0; seg < 2; ++seg) {
    const float* ip; const float* wp; int kn;
    if (seg == 0) { ip = inp; wp = w; kn = nk; }
    else { if (!nk2) break; ip = inp2; wp = w2; kn = nk2; }
    for (int c0 = 0; c0 < kn; c0 += 64) {
      const float4* s4 = (const float4*)(ip + c0 * 64);
      float4* d4 = (float4*)sI;
#pragma unroll
      for (int u = 0; u < 4; ++u) d4[tid + u * 256] = s4[tid + u * 256];
#pragma unroll
      for (int u = 0; u < 4; ++u) {
        const int idx = tid + u * 256, k = idx >> 4, f = idx & 15;
        ((float4*)sW)[idx] = *(const float4*)(wp + (size_t)(c0 + k) * ldw + f * 4);
      }
      __syncthreads();
#pragma unroll 8
      for (int k = 0; k < 64; ++k) {
        const float4 a = *(const float4*)(sI + k * 64 + tb);
        const float4 wv = *(const float4*)(sW + k * 64 + tn);
        acc[0][0] += wv.x * a.x; acc[0][1] += wv.x * a.y; acc[0][2] += wv.x * a.z; acc[0][3] += wv.x * a.w;
        acc[1][0] += wv.y * a.x; acc[1][1] += wv.y * a.y; acc[1][2] += wv.y * a.z; acc[1][3] += wv.y * a.w;
        acc[2][0] += wv.z * a.x; acc[2][1] += wv.z * a.y; acc[2][2] += wv.z * a.z; acc[2][3] += wv.z * a.w;
        acc[3][0] += wv.w * a.x; acc[3][1] += wv.w * a.y; acc[3][2] += wv.w * a.z; acc[3][3] += wv.w * a.w;
      }
      __syncthreads();
    }
  }

  float* po = ((phase == 0) ? g_partA : g_partB) + (size_t)id * 4096;
#pragma unroll
  for (int i = 0; i < 4; ++i) {
    float4 v = {acc[i][0], acc[i][1], acc[i][2], acc[i][3]};
    *(float4*)(po + (tn + i) * 64 + tb) = v;
  }
}

// ---------------- reduce A: z=sigma, r=sigma, rh^T, gx^T, y ----------------
// columns: [0,3072) z | [3072,6144) r | [6144,9216) gx | [9216,9344) y
__global__ __launch_bounds__(256) void reduceA(
    int tau, const float* __restrict__ Bh0, const float* __restrict__ Bhr,
    const float* __restrict__ Bout, float* __restrict__ Out) {
  const int gid = blockIdx.x * 256 + threadIdx.x;  // < 9344*64
  const int b = gid & 63, c = gid >> 6;
  const int par = tau & 1;
  if (c < 6144) {  // z or r gate
    const int gate = (c >= 3072) ? 1 : 0;
    const int cc = c - gate * 3072;
    const int l = cc >> 10, n = cc & 1023;
    const int t_l = tau - l;
    if (t_l < 0 || t_l >= kS) return;
    const int tile = n >> 6, cl = n & 63;
    int base, nks;
    if (l == 0)      { base = gate * 64 + tile * 4;        nks = 4; }
    else if (l == 1) { base = 128 + gate * 128 + tile * 8; nks = 8; }
    else             { base = 384 + gate * 128 + tile * 8; nks = 8; }
    float s = (l == 0) ? Bh0[gate * 1024 + n] : Bhr[(l - 1) * 3072 + gate * 1024 + n];
    for (int j = 0; j < nks; ++j) s += g_partA[(size_t)(base + j) * 4096 + cl * 64 + b];
    const float v = 1.f / (1.f + expf(-s));
    if (gate == 0) {
      g_zT[l * 65536 + n * 64 + b] = v;
    } else {
      const float h = g_hbuf[par * 196608 + l * 65536 + n * 64 + b];
      g_rhT[l * 65536 + n * 64 + b] = v * h;
    }
  } else if (c < 9216) {  // g x-part + bias
    const int cc = c - 6144, l = cc >> 10, n = cc & 1023;
    const int t_l = tau - l;
    if (t_l < 0 || t_l >= kS) return;
    const int tile = n >> 6, cl = n & 63;
    int base, nks;
    if (l == 0)      { base = 640 + tile;     nks = 1; }
    else if (l == 1) { base = 656 + tile * 4; nks = 4; }
    else             { base = 720 + tile * 4; nks = 4; }
    float s = (l == 0) ? Bh0[2048 + n] : Bhr[(l - 1) * 3072 + 2048 + n];
    for (int j = 0; j < nks; ++j) s += g_partA[(size_t)(base + j) * 4096 + cl * 64 + b];
    g_gxT[l * 65536 + n * 64 + b] = s;
  } else {  // y
    const int o = c - 9216, ty = tau - 3;
    if (ty < 0 || ty >= kS) return;
    const int tile = o >> 6, cl = o & 63, base = 784 + tile * 4;
    float s = Bout[o];
    for (int j = 0; j < 4; ++j) s += g_partA[(size_t)(base + j) * 4096 + cl * 64 + b];
    Out[((size_t)b * kS + ty) * kO + o] = s;
  }
}

// ---------------- reduce B: g=tanh(gx+gh), h' = z*h + (1-z)*g ----------------
__global__ __launch_bounds__(256) void reduceB(
    int tau, float* __restrict__ Out) {
  const int gid = blockIdx.x * 256 + threadIdx.x;  // < 3072*64
  const int b = gid & 63, c = gid >> 6;
  const int l = c >> 10, n = c & 1023;
  const int t_l = tau - l;
  if (t_l < 0 || t_l >= kS) return;
  const int par = tau & 1;
  const int tile = n >> 6, cl = n & 63;
  const int base = (l * 16 + tile) * 8;
  float gs = g_gxT[l * 65536 + n * 64 + b];
  for (int j = 0; j < 8; ++j) gs += g_partB[(size_t)(base + j) * 4096 + cl * 64 + b];
  const float g = tanhf(gs);
  const float z = g_zT[l * 65536 + n * 64 + b];
  const float h = g_hbuf[par * 196608 + l * 65536 + n * 64 + b];
  const float hn = z * h + (1.f - z) * g;
  g_hbuf[(1 - par) * 196608 + l * 65536 + n * 64 + b] = hn;
  if (t_l == kS - 1)
    Out[kBSO + ((size_t)b * 3 + l) * 1024 + n] = hn;
}

// ---------------- host ----------------
extern "C" void kernel_launch(void* const* d_in, const int* in_sizes, int n_in,
                              void* d_out, int out_size, void* d_ws, size_t ws_size,
                              hipStream_t stream) {
  const float* X    = (const float*)d_in[0];
  const float* Wx0  = (const float*)d_in[1];
  const float* Wh0  = (const float*)d_in[2];
  const float* bh0  = (const float*)d_in[3];
  const float* Wxr  = (const float*)d_in[4];
  const float* Whr  = (const float*)d_in[5];
  const float* bhr  = (const float*)d_in[6];
  const float* Wout = (const float*)d_in[7];
  const float* bout = (const float*)d_in[8];
  (void)d_ws; (void)ws_size;

  if (n_in != 9 ||
      in_sizes[0] != 64 * 512 * 128 || in_sizes[1] != 3 * 1024 * 128 ||
      in_sizes[2] != 3 * 1024 * 1024 || in_sizes[3] != 3 * 1024 ||
      in_sizes[4] != 2 * 3 * 1024 * 1024 || in_sizes[5] != 2 * 3 * 1024 * 1024 ||
      in_sizes[6] != 2 * 3 * 1024 || in_sizes[7] != 128 * 1024 ||
      in_sizes[8] != 128 || out_size != 64 * 512 * 128 + 64 * 3 * 1024)
    return;  // diagnostic: out stays 0

  float* out = (float*)d_out;

  hipLaunchKernelGGL(zero_hbuf, dim3(1536), dim3(256), 0, stream);
  hipLaunchKernelGGL(transpose_k, dim3(4, 32, 3),   dim3(256), 0, stream, Wx0,  0, 1024, 128);
  hipLaunchKernelGGL(transpose_k, dim3(32, 32, 3),  dim3(256), 0, stream, Wh0,  1, 1024, 1024);
  hipLaunchKernelGGL(transpose_k, dim3(32, 32, 6),  dim3(256), 0, stream, Wxr,  2, 1024, 1024);
  hipLaunchKernelGGL(transpose_k, dim3(32, 32, 6),  dim3(256), 0, stream, Whr,  3, 1024, 1024);
  hipLaunchKernelGGL(transpose_k, dim3(32, 4, 1),   dim3(256), 0, stream, Wout, 4, 128, 1024);
  hipLaunchKernelGGL(transpose_k, dim3(2048, 2, 1), dim3(256), 0, stream, X,    5, 64, 65536);

  for (int tau = 0; tau < kTicks; ++tau) {
    hipLaunchKernelGGL(gemm_tasks, dim3(kTasksA), dim3(256), 0, stream, 0, tau);
    hipLaunchKernelGGL(reduceA, dim3(2336), dim3(256), 0, stream,
                       tau, bh0, bhr, bout, out);
    if (tau < kTicks - 1) {
      hipLaunchKernelGGL(gemm_tasks, dim3(kTasksB), dim3(256), 0, stream, 1, tau);
      hipLaunchKernelGGL(reduceB, dim3(768), dim3(256), 0, stream, tau, out);
    }
  }
}